// Round 20
// baseline (49.295 us; speedup 1.0000x reference)
//
#include <hip/hip_runtime.h>
#include <math.h>

#define DIMS 3
#define NPTS 320
#define HID  128
#define RANK 64
#define LROW 128          // LDS bytes per f2 row, XOR-swizzled
#define NT   3200         // (a, 32-b) tiles
#define GRID 256          // persistent blocks, 1 per CU

typedef __attribute__((ext_vector_type(8)))  short bf16x8;
typedef __attribute__((ext_vector_type(16))) float f32x16;

// round-to-nearest-even float -> bf16 bits
static __device__ __forceinline__ unsigned short f2bf_rn(float x) {
    union { float f; unsigned int u; } v; v.f = x;
    unsigned int r = v.u + 0x7fffu + ((v.u >> 16) & 1u);
    return (unsigned short)(r >> 16);
}
static __device__ __forceinline__ float bf2f(unsigned short h) {
    union { unsigned int u; float f; } v; v.u = ((unsigned int)h) << 16;
    return v.f;
}

// ---------------- Phase 1: per-dim MLP, 4-way k-split (R14, proven best) ----
__global__ __launch_bounds__(512)
void mlp_kernel(const float* __restrict__ xs,
                const float* __restrict__ W0, const float* __restrict__ b0,
                const float* __restrict__ W1, const float* __restrict__ b1,
                const float* __restrict__ W2, const float* __restrict__ b2,
                const float* __restrict__ W3, const float* __restrict__ b3,
                float* __restrict__ f01t,
                unsigned short* __restrict__ f2hi) {
    const int blk = blockIdx.x;
    const int d = blk / NPTS, n = blk % NPTS;
    const int j  = threadIdx.x & (HID - 1);
    const int kq = threadIdx.x >> 7;          // 0..3
    const int k0 = kq * 32;

    __shared__ float ha[HID];
    __shared__ float hb[HID];
    __shared__ float part[4][HID];

    const float x = xs[d * NPTS + n];

    if (kq == 0) {
        ha[j] = tanhf(fmaf(x, W0[d * HID + j], b0[d * HID + j]));
    }
    __syncthreads();

    {
        float acc = 0.0f;
        const float* w = W1 + d * HID * HID + j;
        #pragma unroll 16
        for (int k = 0; k < 32; ++k) acc = fmaf(ha[k0 + k], w[(k0 + k) * HID], acc);
        part[kq][j] = acc;
    }
    __syncthreads();
    if (kq == 0) {
        float s = ((part[0][j] + part[1][j]) + (part[2][j] + part[3][j]))
                  + b1[d * HID + j];
        hb[j] = tanhf(s);
    }
    __syncthreads();

    {
        float acc = 0.0f;
        const float* w = W2 + d * HID * HID + j;
        #pragma unroll 16
        for (int k = 0; k < 32; ++k) acc = fmaf(hb[k0 + k], w[(k0 + k) * HID], acc);
        part[kq][j] = acc;
    }
    __syncthreads();
    if (kq == 0) {
        float s = ((part[0][j] + part[1][j]) + (part[2][j] + part[3][j]))
                  + b2[d * HID + j];
        ha[j] = tanhf(s);
    }
    __syncthreads();

    if (j < RANK) {
        float acc = 0.0f;
        const float* w = W3 + d * HID * RANK + j;
        #pragma unroll 16
        for (int k = 0; k < 32; ++k) acc = fmaf(ha[k0 + k], w[(k0 + k) * RANK], acc);
        part[kq][j] = acc;
    }
    __syncthreads();
    if (kq == 0 && j < RANK) {
        float s = ((part[0][j] + part[1][j]) + (part[2][j] + part[3][j]))
                  + b3[d * RANK + j];
        if (d == 0) {
            f01t[n * RANK + j] = s;                      // f0t[a][r]
        } else if (d == 1) {
            f01t[(NPTS + n) * RANK + j] = s;             // f1t[b][r]
        } else {
            f2hi[n * RANK + j] = f2bf_rn(s);             // single-rounded B
        }
    }
}

// ---------------- Phase 2: write-pipelined CP via 32x32x16 bf16 MFMA --------
// out[a,b,c] = sum_r (f0[a,r]*f1[b,r]) * f2[c,r]
// 256 persistent blocks (1/CU), 128 thr (2 waves). Block owns (a, 32-b,
// all 320 c) tiles. Double-buffered 40 KB LDS output staging; raw s_barrier
// with lgkmcnt-ONLY waits -> global stores are NEVER drained inside the loop
// (vmcnt is FIFO: A-loads issue before the copy stores each iteration, so the
// compiler's counted vmcnt wait retires only the loads). Copy-out is a
// fill-identical contiguous 40 KB dwordx4 stream. Numerics = R14 exactly.
__global__ __launch_bounds__(128)
void cp_mfma_kernel(const float* __restrict__ f01t,
                    const unsigned short* __restrict__ f2hi,
                    float* __restrict__ out) {
    const int tx = threadIdx.x;
    const int w  = tx >> 6;        // wave -> c half
    const int l  = tx & 63;
    const int lc = l & 31;         // A row(b) / B col(c)
    const int hw = l >> 5;         // half-wave -> k sub-group

    __shared__ char  sB[NPTS * LROW];        // 40 KB, f2 swizzled
    __shared__ float stage[2][32 * NPTS];    // 2 x 40 KB output staging

    // ---- stage full f2 once (2560 float4, 20/thread), swizzled ----
    #pragma unroll
    for (int i = 0; i < 20; ++i) {
        int idx = tx + i * 128;               // 0..2559
        int row = idx >> 3;                   // c row
        int g   = (idx & 7) << 4;             // 16B slot within 128B row
        *(float4*)(&sB[row * LROW + (g ^ ((row & 7) << 4))]) =
            ((const float4*)f2hi)[idx];
    }
    __syncthreads();

    float4 L[4][4];   // A-source regs: [ks][0]=f0a [1]=f0b [2]=f1a [3]=f1b
    bf16x8 ahi[4], alo[4];

#define ALOAD(T)                                                               \
    {                                                                          \
        const int a_  = (T) / 10;                                              \
        const int b0_ = ((T) - a_ * 10) * 32;                                  \
        const float* f0p = f01t + (size_t)a_ * RANK + hw * 8;                  \
        const float* f1p = f01t + (size_t)(NPTS + b0_ + lc) * RANK + hw * 8;   \
        _Pragma("unroll")                                                      \
        for (int ks = 0; ks < 4; ++ks) {                                       \
            L[ks][0] = *(const float4*)(f0p + ks * 16);                        \
            L[ks][1] = *(const float4*)(f0p + ks * 16 + 4);                    \
            L[ks][2] = *(const float4*)(f1p + ks * 16);                        \
            L[ks][3] = *(const float4*)(f1p + ks * 16 + 4);                    \
        }                                                                      \
    }

#define ABUILD()                                                               \
    {                                                                          \
        _Pragma("unroll")                                                      \
        for (int ks = 0; ks < 4; ++ks) {                                       \
            float4 f0a = L[ks][0], f0b = L[ks][1];                             \
            float4 f1a = L[ks][2], f1b = L[ks][3];                             \
            float g[8];                                                        \
            g[0] = f1a.x * f0a.x; g[1] = f1a.y * f0a.y;                        \
            g[2] = f1a.z * f0a.z; g[3] = f1a.w * f0a.w;                        \
            g[4] = f1b.x * f0b.x; g[5] = f1b.y * f0b.y;                        \
            g[6] = f1b.z * f0b.z; g[7] = f1b.w * f0b.w;                        \
            _Pragma("unroll")                                                  \
            for (int j = 0; j < 8; ++j) {                                      \
                unsigned short hi = f2bf_rn(g[j]);                             \
                ahi[ks][j] = (short)hi;                                        \
                alo[ks][j] = (short)f2bf_rn(g[j] - bf2f(hi));                  \
            }                                                                  \
        }                                                                      \
    }

#define MFMA_STAGE(BUF)                                                        \
    {                                                                          \
        _Pragma("unroll")                                                      \
        for (int ct = 0; ct < 5; ++ct) {                                       \
            const int crow = w * 160 + ct * 32 + lc;                           \
            const char* rowp = &sB[crow * LROW];                               \
            const int swz = (crow & 7) << 4;                                   \
            f32x16 acc;                                                        \
            _Pragma("unroll")                                                  \
            for (int jj = 0; jj < 16; ++jj) acc[jj] = 0.0f;                    \
            _Pragma("unroll")                                                  \
            for (int ks = 0; ks < 4; ++ks) {                                   \
                const int base = ks * 32 + (hw << 4);                          \
                bf16x8 b = *(const bf16x8*)(rowp + (base ^ swz));              \
                acc = __builtin_amdgcn_mfma_f32_32x32x16_bf16(ahi[ks], b, acc, 0, 0, 0); \
                acc = __builtin_amdgcn_mfma_f32_32x32x16_bf16(alo[ks], b, acc, 0, 0, 0); \
            }                                                                  \
            _Pragma("unroll")                                                  \
            for (int q = 0; q < 16; ++q) {                                     \
                int brow = (q & 3) + 8 * (q >> 2) + 4 * hw;                    \
                stage[BUF][brow * NPTS + crow] = acc[q];                       \
            }                                                                  \
        }                                                                      \
    }

#define COPYOUT(T, BUF)                                                        \
    {                                                                          \
        const int a_  = (T) / 10;                                              \
        const int b0_ = ((T) - a_ * 10) * 32;                                  \
        float4* dst = (float4*)(out + ((size_t)a_ * NPTS + b0_) * NPTS);       \
        const float4* src = (const float4*)stage[BUF];                         \
        float4 tmp[20];                                                        \
        _Pragma("unroll")                                                      \
        for (int p = 0; p < 20; ++p) tmp[p] = src[tx + p * 128];               \
        _Pragma("unroll")                                                      \
        for (int p = 0; p < 20; ++p) dst[tx + p * 128] = tmp[p];               \
    }

    int t = blockIdx.x;
    int cur = 0;

    // ---- prolog: compute first tile into stage[0] ----
    ALOAD(t)
    ABUILD()
    MFMA_STAGE(0)
    asm volatile("s_waitcnt lgkmcnt(0)" ::: "memory");
    __builtin_amdgcn_s_barrier();

    for (;;) {
        const int tn = t + GRID;
        const bool more = (tn < NT);

        if (more) ALOAD(tn)                       // oldest VMEM in queue
        __builtin_amdgcn_sched_barrier(0);        // pin loads before stores
        COPYOUT(t, cur)                           // 40 KB contiguous stores
        if (!more) break;

        ABUILD()                                  // vmcnt wait retires loads only
        MFMA_STAGE(cur ^ 1)
        asm volatile("s_waitcnt lgkmcnt(0)" ::: "memory");
        __builtin_amdgcn_s_barrier();
        t = tn; cur ^= 1;
    }

#undef ALOAD
#undef ABUILD
#undef MFMA_STAGE
#undef COPYOUT
}

extern "C" void kernel_launch(void* const* d_in, const int* in_sizes, int n_in,
                              void* d_out, int out_size, void* d_ws, size_t ws_size,
                              hipStream_t stream) {
    const float* xs = (const float*)d_in[0];
    const float* W0 = (const float*)d_in[1];
    const float* b0 = (const float*)d_in[2];
    const float* W1 = (const float*)d_in[3];
    const float* b1 = (const float*)d_in[4];
    const float* W2 = (const float*)d_in[5];
    const float* b2 = (const float*)d_in[6];
    const float* W3 = (const float*)d_in[7];
    const float* b3 = (const float*)d_in[8];

    // workspace: f01t float[2][NPTS][RANK] | f2hi ushort[NPTS][RANK]
    float* f01t = (float*)d_ws;
    unsigned short* f2hi = (unsigned short*)((char*)d_ws + 2 * NPTS * RANK * 4);
    float* out = (float*)d_out;

    mlp_kernel<<<dim3(DIMS * NPTS), dim3(512), 0, stream>>>(
        xs, W0, b0, W1, b1, W2, b2, W3, b3, f01t, f2hi);

    cp_mfma_kernel<<<dim3(GRID), dim3(128), 0, stream>>>(f01t, f2hi, out);
}

// Round 21
// 37.923 us; speedup vs baseline: 1.2999x; 1.2999x over previous
//
#include <hip/hip_runtime.h>
#include <math.h>

#define DIMS 3
#define NPTS 320
#define HID  128
#define RANK 64
#define CH   160   // c rows per block (half of NPTS)
#define LROW 128   // LDS bytes per c row (single bf16 table), XOR-swizzled

typedef __attribute__((ext_vector_type(8)))  short bf16x8;
typedef __attribute__((ext_vector_type(16))) float f32x16;

// round-to-nearest-even float -> bf16 bits
static __device__ __forceinline__ unsigned short f2bf_rn(float x) {
    union { float f; unsigned int u; } v; v.f = x;
    unsigned int r = v.u + 0x7fffu + ((v.u >> 16) & 1u);
    return (unsigned short)(r >> 16);
}
static __device__ __forceinline__ float bf2f(unsigned short h) {
    union { unsigned int u; float f; } v; v.u = ((unsigned int)h) << 16;
    return v.f;
}

// ---------------- Phase 1: per-dim MLP, 4-way k-split (R14, proven best) ----
// 960 blocks x 512 thr: thread = (hidden unit j, k-quarter). 32-iter partial
// chains (4x shorter), LDS tree-reduce, 4x the waves of the naive version ->
// weight-load latency hidden by TLP (R10/R13 falsified the ILP route).
__global__ __launch_bounds__(512)
void mlp_kernel(const float* __restrict__ xs,
                const float* __restrict__ W0, const float* __restrict__ b0,
                const float* __restrict__ W1, const float* __restrict__ b1,
                const float* __restrict__ W2, const float* __restrict__ b2,
                const float* __restrict__ W3, const float* __restrict__ b3,
                float* __restrict__ f01t,
                unsigned short* __restrict__ f2hi) {
    const int blk = blockIdx.x;
    const int d = blk / NPTS, n = blk % NPTS;
    const int j  = threadIdx.x & (HID - 1);
    const int kq = threadIdx.x >> 7;          // 0..3
    const int k0 = kq * 32;

    __shared__ float ha[HID];
    __shared__ float hb[HID];
    __shared__ float part[4][HID];

    const float x = xs[d * NPTS + n];

    if (kq == 0) {
        ha[j] = tanhf(fmaf(x, W0[d * HID + j], b0[d * HID + j]));
    }
    __syncthreads();

    {
        float acc = 0.0f;
        const float* w = W1 + d * HID * HID + j;
        #pragma unroll 16
        for (int k = 0; k < 32; ++k) acc = fmaf(ha[k0 + k], w[(k0 + k) * HID], acc);
        part[kq][j] = acc;
    }
    __syncthreads();
    if (kq == 0) {
        float s = ((part[0][j] + part[1][j]) + (part[2][j] + part[3][j]))
                  + b1[d * HID + j];
        hb[j] = tanhf(s);
    }
    __syncthreads();

    {
        float acc = 0.0f;
        const float* w = W2 + d * HID * HID + j;
        #pragma unroll 16
        for (int k = 0; k < 32; ++k) acc = fmaf(hb[k0 + k], w[(k0 + k) * HID], acc);
        part[kq][j] = acc;
    }
    __syncthreads();
    if (kq == 0) {
        float s = ((part[0][j] + part[1][j]) + (part[2][j] + part[3][j]))
                  + b2[d * HID + j];
        ha[j] = tanhf(s);
    }
    __syncthreads();

    if (j < RANK) {
        float acc = 0.0f;
        const float* w = W3 + d * HID * RANK + j;
        #pragma unroll 16
        for (int k = 0; k < 32; ++k) acc = fmaf(ha[k0 + k], w[(k0 + k) * RANK], acc);
        part[kq][j] = acc;
    }
    __syncthreads();
    if (kq == 0 && j < RANK) {
        float s = ((part[0][j] + part[1][j]) + (part[2][j] + part[3][j]))
                  + b3[d * RANK + j];
        if (d == 0) {
            f01t[n * RANK + j] = s;                      // f0t[a][r]
        } else if (d == 1) {
            f01t[(NPTS + n) * RANK + j] = s;             // f1t[b][r]
        } else {
            f2hi[n * RANK + j] = f2bf_rn(s);             // single-rounded B
        }
    }
}

// ---------------- Phase 2: persistent-block CP via 32x32x16 bf16 MFMA -------
// R14 configuration (empirical optimum, 37.9 us, reproduced twice):
// 1024 blocks x 128 thr (2 waves), block owns a c-half staged once (20 KB,
// XOR-swizzled); per ct: 4 ds_read_b128 + 8 MFMAs (A hi/lo x B) + 16
// interleaved full-128B-line stores. A built in-register with hi/lo split.
// Twelve orthogonal optimization attempts (occupancy, store patterns,
// pipelining, work distribution) all landed flat or worse - this is the
// practical plateau for this structure.
__global__ __launch_bounds__(128, 2)
void cp_mfma_kernel(const float* __restrict__ f01t,
                    const unsigned short* __restrict__ f2hi,
                    float* __restrict__ out) {
    const int tx = threadIdx.x;
    const int w  = tx >> 6;        // wave -> b sub-tile
    const int l  = tx & 63;
    const int lc = l & 31;         // A row(b) / B col(c) / D col(c)
    const int hw = l >> 5;         // half-wave -> k sub-group

    const int c0 = (blockIdx.x & 1) * CH;

    __shared__ char sB[CH * LROW];   // 20 KB

    // ---- stage c-half of f2 once (1280 float4, 10/thread), swizzled ----
    #pragma unroll
    for (int i = 0; i < 10; ++i) {
        int idx = tx + i * 128;               // 0..1279
        int row = idx >> 3;                   // local c row
        int g   = (idx & 7) << 4;             // 16B slot within 128B row
        *(float4*)(&sB[row * LROW + (g ^ ((row & 7) << 4))]) =
            ((const float4*)f2hi)[c0 * 8 + idx];
    }
    __syncthreads();

    for (int t = blockIdx.x >> 1; t < NPTS * 5; t += 512) {
        const int a   = t / 5;
        const int b0w = (t - a * 5) * 64 + w * 32;
        const float* f0p = f01t + (size_t)a * RANK + hw * 8;
        const float* f1p = f01t + (size_t)(NPTS + b0w + lc) * RANK + hw * 8;

        // ---- A fragments: g[j] = f0[a][k]*f1[b][k], k = ks*16 + hw*8 + j ----
        bf16x8 ahi[4], alo[4];
        #pragma unroll
        for (int ks = 0; ks < 4; ++ks) {
            const int k0 = ks * 16;
            float4 f0a = *(const float4*)(f0p + k0);
            float4 f0b = *(const float4*)(f0p + k0 + 4);
            float4 f1a = *(const float4*)(f1p + k0);
            float4 f1b = *(const float4*)(f1p + k0 + 4);

            float g[8];
            g[0] = f1a.x * f0a.x; g[1] = f1a.y * f0a.y;
            g[2] = f1a.z * f0a.z; g[3] = f1a.w * f0a.w;
            g[4] = f1b.x * f0b.x; g[5] = f1b.y * f0b.y;
            g[6] = f1b.z * f0b.z; g[7] = f1b.w * f0b.w;

            #pragma unroll
            for (int j = 0; j < 8; ++j) {
                unsigned short hi = f2bf_rn(g[j]);
                ahi[ks][j] = (short)hi;
                alo[ks][j] = (short)f2bf_rn(g[j] - bf2f(hi));
            }
        }

        // ---- 5 c-tiles of 32: 4 LDS reads + 8 MFMAs + 16 stores each ----
        #pragma unroll
        for (int ct = 0; ct < 5; ++ct) {
            const char* rowp = &sB[(ct * 32 + lc) * LROW];
            const int swz = ((ct * 32 + lc) & 7) << 4;

            f32x16 acc;
            #pragma unroll
            for (int jj = 0; jj < 16; ++jj) acc[jj] = 0.0f;

            #pragma unroll
            for (int ks = 0; ks < 4; ++ks) {
                const int base = ks * 32 + (hw << 4);       // k slot bytes
                bf16x8 b = *(const bf16x8*)(rowp + (base ^ swz));
                acc = __builtin_amdgcn_mfma_f32_32x32x16_bf16(ahi[ks], b, acc, 0, 0, 0);
                acc = __builtin_amdgcn_mfma_f32_32x32x16_bf16(alo[ks], b, acc, 0, 0, 0);
            }

            // D: col(c)=lc, row(b) = (q&3) + 8*(q>>2) + 4*hw
            float* obase = out + ((size_t)a * NPTS + b0w) * NPTS + c0 + ct * 32 + lc;
            #pragma unroll
            for (int q = 0; q < 16; ++q) {
                int row = (q & 3) + 8 * (q >> 2) + 4 * hw;
                obase[(size_t)row * NPTS] = acc[q];
            }
        }
    }
}

extern "C" void kernel_launch(void* const* d_in, const int* in_sizes, int n_in,
                              void* d_out, int out_size, void* d_ws, size_t ws_size,
                              hipStream_t stream) {
    const float* xs = (const float*)d_in[0];
    const float* W0 = (const float*)d_in[1];
    const float* b0 = (const float*)d_in[2];
    const float* W1 = (const float*)d_in[3];
    const float* b1 = (const float*)d_in[4];
    const float* W2 = (const float*)d_in[5];
    const float* b2 = (const float*)d_in[6];
    const float* W3 = (const float*)d_in[7];
    const float* b3 = (const float*)d_in[8];

    // workspace: f01t float[2][NPTS][RANK] | f2hi ushort[NPTS][RANK]
    float* f01t = (float*)d_ws;
    unsigned short* f2hi = (unsigned short*)((char*)d_ws + 2 * NPTS * RANK * 4);
    float* out = (float*)d_out;

    mlp_kernel<<<dim3(DIMS * NPTS), dim3(512), 0, stream>>>(
        xs, W0, b0, W1, b1, W2, b2, W3, b3, f01t, f2hi);

    cp_mfma_kernel<<<dim3(1024), dim3(128), 0, stream>>>(f01t, f2hi, out);
}